// Round 3
// baseline (1802.378 us; speedup 1.0000x reference)
//
#include <hip/hip_runtime.h>

#define N_NODES 50000
#define N_EDGES 800000
#define IN_DIM 128
#define HID 64
#define N_GRAPHS 256

// ---------------- CSR build: histogram -> scan -> fill ----------------
__global__ __launch_bounds__(256) void hist_kernel(const int* __restrict__ dst,
                                                   int* __restrict__ deg) {
  int i = blockIdx.x * 256 + threadIdx.x;
  if (i < N_EDGES) atomicAdd(&deg[dst[i]], 1);
}

__global__ __launch_bounds__(1024) void scan_kernel(const int* __restrict__ deg,
                                                    int* __restrict__ off,
                                                    int* __restrict__ cursor) {
  __shared__ int ssum[1024];
  const int CH = (N_NODES + 1023) / 1024;  // 49
  const int t = threadIdx.x;
  const int base = t * CH;
  int s = 0;
  for (int i = 0; i < CH; ++i) {
    int n = base + i;
    if (n < N_NODES) s += deg[n];
  }
  ssum[t] = s;
  __syncthreads();
  for (int ofs = 1; ofs < 1024; ofs <<= 1) {
    int v = (t >= ofs) ? ssum[t - ofs] : 0;
    __syncthreads();
    ssum[t] += v;
    __syncthreads();
  }
  int run = (t == 0) ? 0 : ssum[t - 1];
  for (int i = 0; i < CH; ++i) {
    int n = base + i;
    if (n < N_NODES) {
      off[n] = run;
      cursor[n] = run;
      run += deg[n];
    }
  }
  if (t == 1023) off[N_NODES] = run;
}

__global__ __launch_bounds__(256) void fill_kernel(const int* __restrict__ src,
                                                   const int* __restrict__ dst,
                                                   int* __restrict__ cursor,
                                                   int* __restrict__ csr) {
  int i = blockIdx.x * 256 + threadIdx.x;
  if (i < N_EDGES) {
    int p = atomicAdd(&cursor[dst[i]], 1);
    csr[p] = src[i];
  }
}

// ---------------- proj: h = relu(x @ Wp + bp), 2 nodes per wave ----------------
__global__ __launch_bounds__(512, 8) void proj_kernel(
    const float* __restrict__ x, const float* __restrict__ Wp,
    const float* __restrict__ bp, float* __restrict__ h) {
  __shared__ float sW[IN_DIM * HID];  // 32 KB
  __shared__ float sb[HID];
  for (int i = threadIdx.x; i < IN_DIM * HID; i += 512) sW[i] = Wp[i];
  if (threadIdx.x < HID) sb[threadIdx.x] = bp[threadIdx.x];
  __syncthreads();
  const int wave = threadIdx.x >> 6, lane = threadIdx.x & 63;
  const int wv = blockIdx.x * 8 + wave;
  const int nw = gridDim.x * 8;
  for (int n0 = wv * 2; n0 < N_NODES; n0 += nw * 2) {
    const int n1 = n0 + 1;  // N_NODES even, n0 even -> n1 always valid
    float x00 = x[n0 * IN_DIM + lane];
    float x01 = x[n0 * IN_DIM + 64 + lane];
    float x10 = x[n1 * IN_DIM + lane];
    float x11 = x[n1 * IN_DIM + 64 + lane];
    float acc0 = sb[lane], acc1 = acc0;
#pragma unroll
    for (int k = 0; k < 64; ++k) {
      float w = sW[k * HID + lane];
      acc0 = fmaf(__shfl(x00, k), w, acc0);
      acc1 = fmaf(__shfl(x10, k), w, acc1);
    }
#pragma unroll
    for (int k = 0; k < 64; ++k) {
      float w = sW[(64 + k) * HID + lane];
      acc0 = fmaf(__shfl(x01, k), w, acc0);
      acc1 = fmaf(__shfl(x11, k), w, acc1);
    }
    h[n0 * HID + lane] = fmaxf(acc0, 0.0f);
    h[n1 * HID + lane] = fmaxf(acc1, 0.0f);
  }
}

// ------- gather: agg[n] = h[n] + sum_{e} h[csr[e]] ; wave per node, 8-deep ILP -------
__global__ __launch_bounds__(256, 8) void gather_kernel(
    const float* __restrict__ h, const int* __restrict__ off,
    const int* __restrict__ csr, float* __restrict__ agg) {
  const int lane = threadIdx.x & 63;
  const int wv = (blockIdx.x * 256 + threadIdx.x) >> 6;
  const int nw = (gridDim.x * 256) >> 6;
  for (int n = wv; n < N_NODES; n += nw) {
    const int o0 = off[n], o1 = off[n + 1];
    float a0 = h[n * HID + lane];  // self (eps = 0)
    float a1 = 0.f, a2 = 0.f, a3 = 0.f;
    float a4 = 0.f, a5 = 0.f, a6 = 0.f, a7 = 0.f;
    for (int base = o0; base < o1; base += 64) {
      const int cnt = min(64, o1 - base);
      int idxv = (lane < cnt) ? csr[base + lane] : 0;
      int k = 0;
      for (; k + 8 <= cnt; k += 8) {
        int i0 = __shfl(idxv, k + 0), i1 = __shfl(idxv, k + 1);
        int i2 = __shfl(idxv, k + 2), i3 = __shfl(idxv, k + 3);
        int i4 = __shfl(idxv, k + 4), i5 = __shfl(idxv, k + 5);
        int i6 = __shfl(idxv, k + 6), i7 = __shfl(idxv, k + 7);
        a0 += h[i0 * HID + lane];
        a1 += h[i1 * HID + lane];
        a2 += h[i2 * HID + lane];
        a3 += h[i3 * HID + lane];
        a4 += h[i4 * HID + lane];
        a5 += h[i5 * HID + lane];
        a6 += h[i6 * HID + lane];
        a7 += h[i7 * HID + lane];
      }
      for (; k < cnt; ++k) {
        int idx = __shfl(idxv, k);
        a0 += h[idx * HID + lane];
      }
    }
    agg[n * HID + lane] = ((a0 + a1) + (a2 + a3)) + ((a4 + a5) + (a6 + a7));
  }
}

// ------- mlp: out = relu( relu(agg @ W1 + b1) @ W2 + b2 ), 2 nodes per wave -------
__global__ __launch_bounds__(512, 8) void mlp_kernel(
    const float* __restrict__ agg, const float* __restrict__ W1,
    const float* __restrict__ b1, const float* __restrict__ W2,
    const float* __restrict__ b2, float* __restrict__ out) {
  __shared__ float sW1[HID * HID];  // 16 KB
  __shared__ float sW2[HID * HID];  // 16 KB
  __shared__ float sb1[HID], sb2[HID];
  for (int i = threadIdx.x; i < HID * HID; i += 512) {
    sW1[i] = W1[i];
    sW2[i] = W2[i];
  }
  if (threadIdx.x < HID) {
    sb1[threadIdx.x] = b1[threadIdx.x];
    sb2[threadIdx.x] = b2[threadIdx.x];
  }
  __syncthreads();
  const int wave = threadIdx.x >> 6, lane = threadIdx.x & 63;
  const int wv = blockIdx.x * 8 + wave;
  const int nw = gridDim.x * 8;
  for (int n0 = wv * 2; n0 < N_NODES; n0 += nw * 2) {
    const int n1 = n0 + 1;
    float in0 = agg[n0 * HID + lane];
    float in1 = agg[n1 * HID + lane];
    float acc0 = sb1[lane], acc1 = acc0;
#pragma unroll
    for (int k = 0; k < 64; ++k) {
      float w = sW1[k * HID + lane];
      acc0 = fmaf(__shfl(in0, k), w, acc0);
      acc1 = fmaf(__shfl(in1, k), w, acc1);
    }
    float t0 = fmaxf(acc0, 0.0f), t1 = fmaxf(acc1, 0.0f);
    acc0 = sb2[lane];
    acc1 = acc0;
#pragma unroll
    for (int k = 0; k < 64; ++k) {
      float w = sW2[k * HID + lane];
      acc0 = fmaf(__shfl(t0, k), w, acc0);
      acc1 = fmaf(__shfl(t1, k), w, acc1);
    }
    out[n0 * HID + lane] = fmaxf(acc0, 0.0f);
    out[n1 * HID + lane] = fmaxf(acc1, 0.0f);
  }
}

// ------- pool: batch sorted -> one block per graph, 8 waves, plain reduce -------
__global__ __launch_bounds__(512) void pool_kernel(const float* __restrict__ h,
                                                   const int* __restrict__ batch,
                                                   float* __restrict__ out) {
  const int g = blockIdx.x;
  int lo = 0, hi = N_NODES;
  while (lo < hi) {
    int mid = (lo + hi) >> 1;
    if (batch[mid] < g) lo = mid + 1; else hi = mid;
  }
  const int s = lo;
  hi = N_NODES;
  while (lo < hi) {
    int mid = (lo + hi) >> 1;
    if (batch[mid] < g + 1) lo = mid + 1; else hi = mid;
  }
  const int e = lo;
  const int wave = threadIdx.x >> 6, lane = threadIdx.x & 63;
  float a0 = 0.f, a1 = 0.f, a2 = 0.f, a3 = 0.f;
  int n = s + wave;
  for (; n + 24 < e; n += 32) {
    a0 += h[n * HID + lane];
    a1 += h[(n + 8) * HID + lane];
    a2 += h[(n + 16) * HID + lane];
    a3 += h[(n + 24) * HID + lane];
  }
  for (; n < e; n += 8) a0 += h[n * HID + lane];
  __shared__ float red[8][HID];
  red[wave][lane] = ((a0 + a1) + (a2 + a3));
  __syncthreads();
  if (wave == 0) {
    float v = red[0][lane] + red[1][lane] + red[2][lane] + red[3][lane] +
              red[4][lane] + red[5][lane] + red[6][lane] + red[7][lane];
    float cnt = (float)(e - s);
    out[g * HID + lane] = v / fmaxf(cnt, 1.0f);
  }
}

extern "C" void kernel_launch(void* const* d_in, const int* in_sizes, int n_in,
                              void* d_out, int out_size, void* d_ws, size_t ws_size,
                              hipStream_t stream) {
  const float* x    = (const float*)d_in[0];
  const int*   edge = (const int*)d_in[1];
  const int*   batch= (const int*)d_in[2];
  const float* Wp   = (const float*)d_in[3];
  const float* bp   = (const float*)d_in[4];
  const float* W1_0 = (const float*)d_in[5];
  const float* b1_0 = (const float*)d_in[6];
  const float* W2_0 = (const float*)d_in[7];
  const float* b2_0 = (const float*)d_in[8];
  const float* W1_1 = (const float*)d_in[9];
  const float* b1_1 = (const float*)d_in[10];
  const float* W2_1 = (const float*)d_in[11];
  const float* b2_1 = (const float*)d_in[12];
  const int* src = edge;
  const int* dst = edge + N_EDGES;
  float* out = (float*)d_out;

  const size_t NB = (size_t)N_NODES * HID;
  float* bufA = (float*)d_ws;       // h
  float* bufB = bufA + NB;          // agg
  float* bufC = bufB + NB;          // mlp out
  int* deg    = (int*)(bufC + NB);
  int* off    = deg + N_NODES;
  int* cursor = off + N_NODES + 1;
  int* csr    = cursor + N_NODES;   // 800000 ints

  dim3 b256(256), b512(512);
  const int EG = (N_EDGES + 255) / 256;

  // CSR build
  hipMemsetAsync(deg, 0, N_NODES * sizeof(int), stream);
  hist_kernel<<<EG, b256, 0, stream>>>(dst, deg);
  scan_kernel<<<1, 1024, 0, stream>>>(deg, off, cursor);
  fill_kernel<<<EG, b256, 0, stream>>>(src, dst, cursor, csr);

  // h0 -> bufA
  proj_kernel<<<3125, b512, 0, stream>>>(x, Wp, bp, bufA);

  // layer 0
  gather_kernel<<<12500, b256, 0, stream>>>(bufA, off, csr, bufB);
  mlp_kernel<<<3125, b512, 0, stream>>>(bufB, W1_0, b1_0, W2_0, b2_0, bufC);

  // layer 1
  gather_kernel<<<12500, b256, 0, stream>>>(bufC, off, csr, bufB);
  mlp_kernel<<<3125, b512, 0, stream>>>(bufB, W1_1, b1_1, W2_1, b2_1, bufA);

  // pool
  pool_kernel<<<N_GRAPHS, b512, 0, stream>>>(bufA, batch, out);
}

// Round 4
// 1048.722 us; speedup vs baseline: 1.7186x; 1.7186x over previous
//
#include <hip/hip_runtime.h>

#define N_NODES 50000
#define N_EDGES 800000
#define IN_DIM 128
#define HID 64
#define N_GRAPHS 256

// ---------------- CSR build: histogram -> scan -> fill ----------------
__global__ __launch_bounds__(256) void hist_kernel(const int* __restrict__ dst,
                                                   int* __restrict__ deg) {
  int i = blockIdx.x * 256 + threadIdx.x;
  if (i < N_EDGES) atomicAdd(&deg[dst[i]], 1);
}

__global__ __launch_bounds__(1024) void scan_kernel(const int* __restrict__ deg,
                                                    int* __restrict__ off,
                                                    int* __restrict__ cursor) {
  __shared__ int ssum[1024];
  const int CH = (N_NODES + 1023) / 1024;  // 49
  const int t = threadIdx.x;
  const int base = t * CH;
  int s = 0;
  for (int i = 0; i < CH; ++i) {
    int n = base + i;
    if (n < N_NODES) s += deg[n];
  }
  ssum[t] = s;
  __syncthreads();
  for (int ofs = 1; ofs < 1024; ofs <<= 1) {
    int v = (t >= ofs) ? ssum[t - ofs] : 0;
    __syncthreads();
    ssum[t] += v;
    __syncthreads();
  }
  int run = (t == 0) ? 0 : ssum[t - 1];
  for (int i = 0; i < CH; ++i) {
    int n = base + i;
    if (n < N_NODES) {
      off[n] = run;
      cursor[n] = run;
      run += deg[n];
    }
  }
  if (t == 1023) off[N_NODES] = run;
}

__global__ __launch_bounds__(256) void fill_kernel(const int* __restrict__ src,
                                                   const int* __restrict__ dst,
                                                   int* __restrict__ cursor,
                                                   int* __restrict__ csr) {
  int i = blockIdx.x * 256 + threadIdx.x;
  if (i < N_EDGES) {
    int p = atomicAdd(&cursor[dst[i]], 1);
    csr[p] = src[i];
  }
}

// ---------------- proj: h = relu(x @ Wp + bp), 2 nodes per wave ----------------
// launch_bounds (512,4): VGPR cap 128 -- (512,8) capped at 32 and spilled ~2.2GB/launch (round-3 post-mortem)
__global__ __launch_bounds__(512, 4) void proj_kernel(
    const float* __restrict__ x, const float* __restrict__ Wp,
    const float* __restrict__ bp, float* __restrict__ h) {
  __shared__ float sW[IN_DIM * HID];  // 32 KB
  __shared__ float sb[HID];
  for (int i = threadIdx.x; i < IN_DIM * HID; i += 512) sW[i] = Wp[i];
  if (threadIdx.x < HID) sb[threadIdx.x] = bp[threadIdx.x];
  __syncthreads();
  const int wave = threadIdx.x >> 6, lane = threadIdx.x & 63;
  const int wv = blockIdx.x * 8 + wave;
  const int nw = gridDim.x * 8;
  for (int n0 = wv * 2; n0 < N_NODES; n0 += nw * 2) {
    const int n1 = n0 + 1;  // N_NODES even, n0 even -> n1 always valid
    float x00 = x[n0 * IN_DIM + lane];
    float x01 = x[n0 * IN_DIM + 64 + lane];
    float x10 = x[n1 * IN_DIM + lane];
    float x11 = x[n1 * IN_DIM + 64 + lane];
    float acc0 = sb[lane], acc1 = acc0;
#pragma unroll
    for (int k = 0; k < 64; ++k) {
      float w = sW[k * HID + lane];
      acc0 = fmaf(__shfl(x00, k), w, acc0);
      acc1 = fmaf(__shfl(x10, k), w, acc1);
    }
#pragma unroll
    for (int k = 0; k < 64; ++k) {
      float w = sW[(64 + k) * HID + lane];
      acc0 = fmaf(__shfl(x01, k), w, acc0);
      acc1 = fmaf(__shfl(x11, k), w, acc1);
    }
    h[n0 * HID + lane] = fmaxf(acc0, 0.0f);
    h[n1 * HID + lane] = fmaxf(acc1, 0.0f);
  }
}

// ------- gather: agg[n] = h[n] + sum_{e} h[csr[e]] ; wave per node, 8-deep ILP -------
__global__ __launch_bounds__(256, 8) void gather_kernel(
    const float* __restrict__ h, const int* __restrict__ off,
    const int* __restrict__ csr, float* __restrict__ agg) {
  const int lane = threadIdx.x & 63;
  const int wv = (blockIdx.x * 256 + threadIdx.x) >> 6;
  const int nw = (gridDim.x * 256) >> 6;
  for (int n = wv; n < N_NODES; n += nw) {
    const int o0 = off[n], o1 = off[n + 1];
    float a0 = h[n * HID + lane];  // self (eps = 0)
    float a1 = 0.f, a2 = 0.f, a3 = 0.f;
    float a4 = 0.f, a5 = 0.f, a6 = 0.f, a7 = 0.f;
    for (int base = o0; base < o1; base += 64) {
      const int cnt = min(64, o1 - base);
      int idxv = (lane < cnt) ? csr[base + lane] : 0;
      int k = 0;
      for (; k + 8 <= cnt; k += 8) {
        int i0 = __shfl(idxv, k + 0), i1 = __shfl(idxv, k + 1);
        int i2 = __shfl(idxv, k + 2), i3 = __shfl(idxv, k + 3);
        int i4 = __shfl(idxv, k + 4), i5 = __shfl(idxv, k + 5);
        int i6 = __shfl(idxv, k + 6), i7 = __shfl(idxv, k + 7);
        a0 += h[i0 * HID + lane];
        a1 += h[i1 * HID + lane];
        a2 += h[i2 * HID + lane];
        a3 += h[i3 * HID + lane];
        a4 += h[i4 * HID + lane];
        a5 += h[i5 * HID + lane];
        a6 += h[i6 * HID + lane];
        a7 += h[i7 * HID + lane];
      }
      for (; k < cnt; ++k) {
        int idx = __shfl(idxv, k);
        a0 += h[idx * HID + lane];
      }
    }
    agg[n * HID + lane] = ((a0 + a1) + (a2 + a3)) + ((a4 + a5) + (a6 + a7));
  }
}

// ------- mlp: out = relu( relu(agg @ W1 + b1) @ W2 + b2 ), 2 nodes per wave -------
__global__ __launch_bounds__(512, 4) void mlp_kernel(
    const float* __restrict__ agg, const float* __restrict__ W1,
    const float* __restrict__ b1, const float* __restrict__ W2,
    const float* __restrict__ b2, float* __restrict__ out) {
  __shared__ float sW1[HID * HID];  // 16 KB
  __shared__ float sW2[HID * HID];  // 16 KB
  __shared__ float sb1[HID], sb2[HID];
  for (int i = threadIdx.x; i < HID * HID; i += 512) {
    sW1[i] = W1[i];
    sW2[i] = W2[i];
  }
  if (threadIdx.x < HID) {
    sb1[threadIdx.x] = b1[threadIdx.x];
    sb2[threadIdx.x] = b2[threadIdx.x];
  }
  __syncthreads();
  const int wave = threadIdx.x >> 6, lane = threadIdx.x & 63;
  const int wv = blockIdx.x * 8 + wave;
  const int nw = gridDim.x * 8;
  for (int n0 = wv * 2; n0 < N_NODES; n0 += nw * 2) {
    const int n1 = n0 + 1;
    float in0 = agg[n0 * HID + lane];
    float in1 = agg[n1 * HID + lane];
    float acc0 = sb1[lane], acc1 = acc0;
#pragma unroll
    for (int k = 0; k < 64; ++k) {
      float w = sW1[k * HID + lane];
      acc0 = fmaf(__shfl(in0, k), w, acc0);
      acc1 = fmaf(__shfl(in1, k), w, acc1);
    }
    float t0 = fmaxf(acc0, 0.0f), t1 = fmaxf(acc1, 0.0f);
    acc0 = sb2[lane];
    acc1 = acc0;
#pragma unroll
    for (int k = 0; k < 64; ++k) {
      float w = sW2[k * HID + lane];
      acc0 = fmaf(__shfl(t0, k), w, acc0);
      acc1 = fmaf(__shfl(t1, k), w, acc1);
    }
    out[n0 * HID + lane] = fmaxf(acc0, 0.0f);
    out[n1 * HID + lane] = fmaxf(acc1, 0.0f);
  }
}

// ------- pool: batch sorted -> one block per graph, 8 waves, plain reduce -------
__global__ __launch_bounds__(512) void pool_kernel(const float* __restrict__ h,
                                                   const int* __restrict__ batch,
                                                   float* __restrict__ out) {
  const int g = blockIdx.x;
  int lo = 0, hi = N_NODES;
  while (lo < hi) {
    int mid = (lo + hi) >> 1;
    if (batch[mid] < g) lo = mid + 1; else hi = mid;
  }
  const int s = lo;
  hi = N_NODES;
  while (lo < hi) {
    int mid = (lo + hi) >> 1;
    if (batch[mid] < g + 1) lo = mid + 1; else hi = mid;
  }
  const int e = lo;
  const int wave = threadIdx.x >> 6, lane = threadIdx.x & 63;
  float a0 = 0.f, a1 = 0.f, a2 = 0.f, a3 = 0.f;
  int n = s + wave;
  for (; n + 24 < e; n += 32) {
    a0 += h[n * HID + lane];
    a1 += h[(n + 8) * HID + lane];
    a2 += h[(n + 16) * HID + lane];
    a3 += h[(n + 24) * HID + lane];
  }
  for (; n < e; n += 8) a0 += h[n * HID + lane];
  __shared__ float red[8][HID];
  red[wave][lane] = ((a0 + a1) + (a2 + a3));
  __syncthreads();
  if (wave == 0) {
    float v = red[0][lane] + red[1][lane] + red[2][lane] + red[3][lane] +
              red[4][lane] + red[5][lane] + red[6][lane] + red[7][lane];
    float cnt = (float)(e - s);
    out[g * HID + lane] = v / fmaxf(cnt, 1.0f);
  }
}

extern "C" void kernel_launch(void* const* d_in, const int* in_sizes, int n_in,
                              void* d_out, int out_size, void* d_ws, size_t ws_size,
                              hipStream_t stream) {
  const float* x    = (const float*)d_in[0];
  const int*   edge = (const int*)d_in[1];
  const int*   batch= (const int*)d_in[2];
  const float* Wp   = (const float*)d_in[3];
  const float* bp   = (const float*)d_in[4];
  const float* W1_0 = (const float*)d_in[5];
  const float* b1_0 = (const float*)d_in[6];
  const float* W2_0 = (const float*)d_in[7];
  const float* b2_0 = (const float*)d_in[8];
  const float* W1_1 = (const float*)d_in[9];
  const float* b1_1 = (const float*)d_in[10];
  const float* W2_1 = (const float*)d_in[11];
  const float* b2_1 = (const float*)d_in[12];
  const int* src = edge;
  const int* dst = edge + N_EDGES;
  float* out = (float*)d_out;

  const size_t NB = (size_t)N_NODES * HID;
  float* bufA = (float*)d_ws;       // h
  float* bufB = bufA + NB;          // agg
  float* bufC = bufB + NB;          // mlp out
  int* deg    = (int*)(bufC + NB);
  int* off    = deg + N_NODES;
  int* cursor = off + N_NODES + 1;
  int* csr    = cursor + N_NODES;   // 800000 ints

  dim3 b256(256), b512(512);
  const int EG = (N_EDGES + 255) / 256;

  // CSR build
  hipMemsetAsync(deg, 0, N_NODES * sizeof(int), stream);
  hist_kernel<<<EG, b256, 0, stream>>>(dst, deg);
  scan_kernel<<<1, 1024, 0, stream>>>(deg, off, cursor);
  fill_kernel<<<EG, b256, 0, stream>>>(src, dst, cursor, csr);

  // h0 -> bufA
  proj_kernel<<<3125, b512, 0, stream>>>(x, Wp, bp, bufA);

  // layer 0
  gather_kernel<<<12500, b256, 0, stream>>>(bufA, off, csr, bufB);
  mlp_kernel<<<3125, b512, 0, stream>>>(bufB, W1_0, b1_0, W2_0, b2_0, bufC);

  // layer 1
  gather_kernel<<<12500, b256, 0, stream>>>(bufC, off, csr, bufB);
  mlp_kernel<<<3125, b512, 0, stream>>>(bufB, W1_1, b1_1, W2_1, b2_1, bufA);

  // pool
  pool_kernel<<<N_GRAPHS, b512, 0, stream>>>(bufA, batch, out);
}

// Round 5
// 517.763 us; speedup vs baseline: 3.4811x; 2.0255x over previous
//
#include <hip/hip_runtime.h>

#define N_NODES 50000
#define N_EDGES 800000
#define IN_DIM 128
#define HID 64
#define N_GRAPHS 256

// NOTE (rounds 3-4 post-mortem): any __launch_bounds__ with a min-waves 2nd arg
// made hipcc cap VGPRs at HALF the expected budget and spill ~1.1 GB of scratch
// per dispatch (VGPR_Count 32/64, WRITE_SIZE 1.12 GB, VALUBusy 3-4%).
// Plain __launch_bounds__(256) measured clean in round 2 (VGPR=112, no spill).

// ---------------- CSR build: histogram -> scan -> fill ----------------
__global__ __launch_bounds__(256) void hist_kernel(const int* __restrict__ dst,
                                                   int* __restrict__ deg) {
  int i = blockIdx.x * 256 + threadIdx.x;
  if (i < N_EDGES) atomicAdd(&deg[dst[i]], 1);
}

__global__ __launch_bounds__(1024) void scan_kernel(const int* __restrict__ deg,
                                                    int* __restrict__ off,
                                                    int* __restrict__ cursor) {
  __shared__ int ssum[1024];
  const int CH = (N_NODES + 1023) / 1024;  // 49
  const int t = threadIdx.x;
  const int base = t * CH;
  int s = 0;
  for (int i = 0; i < CH; ++i) {
    int n = base + i;
    if (n < N_NODES) s += deg[n];
  }
  ssum[t] = s;
  __syncthreads();
  for (int ofs = 1; ofs < 1024; ofs <<= 1) {
    int v = (t >= ofs) ? ssum[t - ofs] : 0;
    __syncthreads();
    ssum[t] += v;
    __syncthreads();
  }
  int run = (t == 0) ? 0 : ssum[t - 1];
  for (int i = 0; i < CH; ++i) {
    int n = base + i;
    if (n < N_NODES) {
      off[n] = run;
      cursor[n] = run;
      run += deg[n];
    }
  }
  if (t == 1023) off[N_NODES] = run;
}

__global__ __launch_bounds__(256) void fill_kernel(const int* __restrict__ src,
                                                   const int* __restrict__ dst,
                                                   int* __restrict__ cursor,
                                                   int* __restrict__ csr) {
  int i = blockIdx.x * 256 + threadIdx.x;
  if (i < N_EDGES) {
    int p = atomicAdd(&cursor[dst[i]], 1);
    csr[p] = src[i];
  }
}

// ---------------- proj: h = relu(x @ Wp + bp), one wave per node ----------------
__global__ __launch_bounds__(256) void proj_kernel(
    const float* __restrict__ x, const float* __restrict__ Wp,
    const float* __restrict__ bp, float* __restrict__ h) {
  __shared__ float sW[IN_DIM * HID];  // 32 KB
  __shared__ float sb[HID];
  for (int i = threadIdx.x; i < IN_DIM * HID; i += 256) sW[i] = Wp[i];
  if (threadIdx.x < HID) sb[threadIdx.x] = bp[threadIdx.x];
  __syncthreads();
  const int wave = threadIdx.x >> 6, lane = threadIdx.x & 63;
  const int nwaves = gridDim.x * 4;
  for (int n = blockIdx.x * 4 + wave; n < N_NODES; n += nwaves) {
    float x0 = x[n * IN_DIM + lane];
    float x1 = x[n * IN_DIM + 64 + lane];
    float acc = sb[lane];
#pragma unroll
    for (int k = 0; k < 64; ++k) acc = fmaf(__shfl(x0, k), sW[k * HID + lane], acc);
#pragma unroll
    for (int k = 0; k < 64; ++k) acc = fmaf(__shfl(x1, k), sW[(64 + k) * HID + lane], acc);
    h[n * HID + lane] = fmaxf(acc, 0.0f);
  }
}

// ------- gather: agg[n] = h[n] + sum_{e} h[csr[e]] ; wave per node, 8-deep ILP -------
__global__ __launch_bounds__(256) void gather_kernel(
    const float* __restrict__ h, const int* __restrict__ off,
    const int* __restrict__ csr, float* __restrict__ agg) {
  const int lane = threadIdx.x & 63;
  const int wv = (blockIdx.x * 256 + threadIdx.x) >> 6;
  const int nw = (gridDim.x * 256) >> 6;
  for (int n = wv; n < N_NODES; n += nw) {
    const int o0 = off[n], o1 = off[n + 1];
    float a0 = h[n * HID + lane];  // self (eps = 0)
    float a1 = 0.f, a2 = 0.f, a3 = 0.f;
    float a4 = 0.f, a5 = 0.f, a6 = 0.f, a7 = 0.f;
    for (int base = o0; base < o1; base += 64) {
      const int cnt = min(64, o1 - base);
      int idxv = (lane < cnt) ? csr[base + lane] : 0;
      int k = 0;
      for (; k + 8 <= cnt; k += 8) {
        int i0 = __shfl(idxv, k + 0), i1 = __shfl(idxv, k + 1);
        int i2 = __shfl(idxv, k + 2), i3 = __shfl(idxv, k + 3);
        int i4 = __shfl(idxv, k + 4), i5 = __shfl(idxv, k + 5);
        int i6 = __shfl(idxv, k + 6), i7 = __shfl(idxv, k + 7);
        a0 += h[i0 * HID + lane];
        a1 += h[i1 * HID + lane];
        a2 += h[i2 * HID + lane];
        a3 += h[i3 * HID + lane];
        a4 += h[i4 * HID + lane];
        a5 += h[i5 * HID + lane];
        a6 += h[i6 * HID + lane];
        a7 += h[i7 * HID + lane];
      }
      for (; k < cnt; ++k) {
        int idx = __shfl(idxv, k);
        a0 += h[idx * HID + lane];
      }
    }
    agg[n * HID + lane] = ((a0 + a1) + (a2 + a3)) + ((a4 + a5) + (a6 + a7));
  }
}

// ------- mlp: out = relu( relu(agg @ W1 + b1) @ W2 + b2 ), one wave per node -------
__global__ __launch_bounds__(256) void mlp_kernel(
    const float* __restrict__ agg, const float* __restrict__ W1,
    const float* __restrict__ b1, const float* __restrict__ W2,
    const float* __restrict__ b2, float* __restrict__ out) {
  __shared__ float sW1[HID * HID];  // 16 KB
  __shared__ float sW2[HID * HID];  // 16 KB
  __shared__ float sb1[HID], sb2[HID];
  for (int i = threadIdx.x; i < HID * HID; i += 256) {
    sW1[i] = W1[i];
    sW2[i] = W2[i];
  }
  if (threadIdx.x < HID) {
    sb1[threadIdx.x] = b1[threadIdx.x];
    sb2[threadIdx.x] = b2[threadIdx.x];
  }
  __syncthreads();
  const int wave = threadIdx.x >> 6, lane = threadIdx.x & 63;
  const int nwaves = gridDim.x * 4;
  for (int n = blockIdx.x * 4 + wave; n < N_NODES; n += nwaves) {
    float in = agg[n * HID + lane];
    float acc = sb1[lane];
#pragma unroll
    for (int k = 0; k < 64; ++k) acc = fmaf(__shfl(in, k), sW1[k * HID + lane], acc);
    float t = fmaxf(acc, 0.0f);
    acc = sb2[lane];
#pragma unroll
    for (int k = 0; k < 64; ++k) acc = fmaf(__shfl(t, k), sW2[k * HID + lane], acc);
    out[n * HID + lane] = fmaxf(acc, 0.0f);
  }
}

// ------- pool: batch sorted -> one block per graph, binary-search range -------
__global__ __launch_bounds__(256) void pool_kernel(const float* __restrict__ h,
                                                   const int* __restrict__ batch,
                                                   float* __restrict__ out) {
  const int g = blockIdx.x;
  int lo = 0, hi = N_NODES;
  while (lo < hi) {
    int mid = (lo + hi) >> 1;
    if (batch[mid] < g) lo = mid + 1; else hi = mid;
  }
  const int s = lo;
  hi = N_NODES;
  while (lo < hi) {
    int mid = (lo + hi) >> 1;
    if (batch[mid] < g + 1) lo = mid + 1; else hi = mid;
  }
  const int e = lo;
  const int wave = threadIdx.x >> 6, lane = threadIdx.x & 63;
  float a0 = 0.f, a1 = 0.f, a2 = 0.f, a3 = 0.f;
  int n = s + wave;
  for (; n + 12 < e; n += 16) {
    a0 += h[n * HID + lane];
    a1 += h[(n + 4) * HID + lane];
    a2 += h[(n + 8) * HID + lane];
    a3 += h[(n + 12) * HID + lane];
  }
  for (; n < e; n += 4) a0 += h[n * HID + lane];
  __shared__ float red[4][HID];
  red[wave][lane] = ((a0 + a1) + (a2 + a3));
  __syncthreads();
  if (wave == 0) {
    float v = red[0][lane] + red[1][lane] + red[2][lane] + red[3][lane];
    float cnt = (float)(e - s);
    out[g * HID + lane] = v / fmaxf(cnt, 1.0f);
  }
}

extern "C" void kernel_launch(void* const* d_in, const int* in_sizes, int n_in,
                              void* d_out, int out_size, void* d_ws, size_t ws_size,
                              hipStream_t stream) {
  const float* x    = (const float*)d_in[0];
  const int*   edge = (const int*)d_in[1];
  const int*   batch= (const int*)d_in[2];
  const float* Wp   = (const float*)d_in[3];
  const float* bp   = (const float*)d_in[4];
  const float* W1_0 = (const float*)d_in[5];
  const float* b1_0 = (const float*)d_in[6];
  const float* W2_0 = (const float*)d_in[7];
  const float* b2_0 = (const float*)d_in[8];
  const float* W1_1 = (const float*)d_in[9];
  const float* b1_1 = (const float*)d_in[10];
  const float* W2_1 = (const float*)d_in[11];
  const float* b2_1 = (const float*)d_in[12];
  const int* src = edge;
  const int* dst = edge + N_EDGES;
  float* out = (float*)d_out;

  const size_t NB = (size_t)N_NODES * HID;
  float* bufA = (float*)d_ws;       // h
  float* bufB = bufA + NB;          // agg
  float* bufC = bufB + NB;          // mlp out
  int* deg    = (int*)(bufC + NB);
  int* off    = deg + N_NODES;
  int* cursor = off + N_NODES + 1;
  int* csr    = cursor + N_NODES;   // 800000 ints

  dim3 b256(256);
  const int EG = (N_EDGES + 255) / 256;

  // CSR build
  hipMemsetAsync(deg, 0, N_NODES * sizeof(int), stream);
  hist_kernel<<<EG, b256, 0, stream>>>(dst, deg);
  scan_kernel<<<1, 1024, 0, stream>>>(deg, off, cursor);
  fill_kernel<<<EG, b256, 0, stream>>>(src, dst, cursor, csr);

  // h0 -> bufA
  proj_kernel<<<2048, b256, 0, stream>>>(x, Wp, bp, bufA);

  // layer 0
  gather_kernel<<<12500, b256, 0, stream>>>(bufA, off, csr, bufB);
  mlp_kernel<<<2048, b256, 0, stream>>>(bufB, W1_0, b1_0, W2_0, b2_0, bufC);

  // layer 1
  gather_kernel<<<12500, b256, 0, stream>>>(bufC, off, csr, bufB);
  mlp_kernel<<<2048, b256, 0, stream>>>(bufB, W1_1, b1_1, W2_1, b2_1, bufA);

  // pool
  pool_kernel<<<N_GRAPHS, b256, 0, stream>>>(bufA, batch, out);
}

// Round 6
// 405.078 us; speedup vs baseline: 4.4495x; 1.2782x over previous
//
#include <hip/hip_runtime.h>

#define N_NODES 50000
#define N_EDGES 800000
#define IN_DIM 128
#define HID 64
#define N_GRAPHS 256
#define SCAN_BLOCKS ((N_NODES + 255) / 256)  // 196

// NOTE (rounds 3-4 post-mortem): __launch_bounds__ with a min-waves 2nd arg made
// hipcc cap VGPRs at HALF the computed budget and spill ~1.1 GB/dispatch.
// Plain __launch_bounds__(256) measured clean (VGPR=112, no spill).
// NOTE (round 5): single-block scan = 125 us of one-CU latency; now hierarchical.

// ---------------- CSR build: histogram -> 3-phase scan -> fill ----------------
__global__ __launch_bounds__(256) void hist_kernel(const int* __restrict__ dst,
                                                   int* __restrict__ deg) {
  int i = blockIdx.x * 256 + threadIdx.x;
  if (i < N_EDGES) atomicAdd(&deg[dst[i]], 1);
}

// phase 1: per-block exclusive scan of 256 degrees, emit block sums
__global__ __launch_bounds__(256) void scan1_kernel(const int* __restrict__ deg,
                                                    int* __restrict__ off,
                                                    int* __restrict__ blocksum) {
  __shared__ int s[256];
  const int t = threadIdx.x;
  const int i = blockIdx.x * 256 + t;
  int v = (i < N_NODES) ? deg[i] : 0;
  s[t] = v;
  __syncthreads();
#pragma unroll
  for (int ofs = 1; ofs < 256; ofs <<= 1) {
    int u = (t >= ofs) ? s[t - ofs] : 0;
    __syncthreads();
    s[t] += u;
    __syncthreads();
  }
  if (i < N_NODES) off[i] = s[t] - v;  // exclusive within block
  if (t == 255) blocksum[blockIdx.x] = s[255];
}

// phase 2: single block scans the block sums; also writes off[N_NODES] = total
__global__ __launch_bounds__(256) void scan2_kernel(int* __restrict__ blocksum,
                                                    int* __restrict__ blockpref,
                                                    int* __restrict__ off) {
  __shared__ int s[256];
  const int t = threadIdx.x;
  int v = (t < SCAN_BLOCKS) ? blocksum[t] : 0;
  s[t] = v;
  __syncthreads();
#pragma unroll
  for (int ofs = 1; ofs < 256; ofs <<= 1) {
    int u = (t >= ofs) ? s[t - ofs] : 0;
    __syncthreads();
    s[t] += u;
    __syncthreads();
  }
  if (t < SCAN_BLOCKS) blockpref[t] = s[t] - v;  // exclusive block prefix
  if (t == 255) off[N_NODES] = s[255];           // grand total (= N_EDGES)
}

// phase 3: add block prefix, materialize off and cursor
__global__ __launch_bounds__(256) void scan3_kernel(int* __restrict__ off,
                                                    const int* __restrict__ blockpref,
                                                    int* __restrict__ cursor) {
  const int i = blockIdx.x * 256 + threadIdx.x;
  if (i < N_NODES) {
    int o = off[i] + blockpref[blockIdx.x];
    off[i] = o;
    cursor[i] = o;
  }
}

__global__ __launch_bounds__(256) void fill_kernel(const int* __restrict__ src,
                                                   const int* __restrict__ dst,
                                                   int* __restrict__ cursor,
                                                   int* __restrict__ csr) {
  int i = blockIdx.x * 256 + threadIdx.x;
  if (i < N_EDGES) {
    int p = atomicAdd(&cursor[dst[i]], 1);
    csr[p] = src[i];
  }
}

// ---------------- proj: h = relu(x @ Wp + bp), one wave per node ----------------
__global__ __launch_bounds__(256) void proj_kernel(
    const float* __restrict__ x, const float* __restrict__ Wp,
    const float* __restrict__ bp, float* __restrict__ h) {
  __shared__ float sW[IN_DIM * HID];  // 32 KB
  __shared__ float sb[HID];
  for (int i = threadIdx.x; i < IN_DIM * HID; i += 256) sW[i] = Wp[i];
  if (threadIdx.x < HID) sb[threadIdx.x] = bp[threadIdx.x];
  __syncthreads();
  const int wave = threadIdx.x >> 6, lane = threadIdx.x & 63;
  const int nwaves = gridDim.x * 4;
  for (int n = blockIdx.x * 4 + wave; n < N_NODES; n += nwaves) {
    float x0 = x[n * IN_DIM + lane];
    float x1 = x[n * IN_DIM + 64 + lane];
    float acc = sb[lane];
#pragma unroll
    for (int k = 0; k < 64; ++k) acc = fmaf(__shfl(x0, k), sW[k * HID + lane], acc);
#pragma unroll
    for (int k = 0; k < 64; ++k) acc = fmaf(__shfl(x1, k), sW[(64 + k) * HID + lane], acc);
    h[n * HID + lane] = fmaxf(acc, 0.0f);
  }
}

// ------- gather: agg[n] = h[n] + sum_{e} h[csr[e]] ; wave per node, 8-deep ILP -------
__global__ __launch_bounds__(256) void gather_kernel(
    const float* __restrict__ h, const int* __restrict__ off,
    const int* __restrict__ csr, float* __restrict__ agg) {
  const int lane = threadIdx.x & 63;
  const int wv = (blockIdx.x * 256 + threadIdx.x) >> 6;
  const int nw = (gridDim.x * 256) >> 6;
  for (int n = wv; n < N_NODES; n += nw) {
    const int o0 = off[n], o1 = off[n + 1];
    float a0 = h[n * HID + lane];  // self (eps = 0)
    float a1 = 0.f, a2 = 0.f, a3 = 0.f;
    float a4 = 0.f, a5 = 0.f, a6 = 0.f, a7 = 0.f;
    for (int base = o0; base < o1; base += 64) {
      const int cnt = min(64, o1 - base);
      int idxv = (lane < cnt) ? csr[base + lane] : 0;
      int k = 0;
      for (; k + 8 <= cnt; k += 8) {
        int i0 = __shfl(idxv, k + 0), i1 = __shfl(idxv, k + 1);
        int i2 = __shfl(idxv, k + 2), i3 = __shfl(idxv, k + 3);
        int i4 = __shfl(idxv, k + 4), i5 = __shfl(idxv, k + 5);
        int i6 = __shfl(idxv, k + 6), i7 = __shfl(idxv, k + 7);
        a0 += h[i0 * HID + lane];
        a1 += h[i1 * HID + lane];
        a2 += h[i2 * HID + lane];
        a3 += h[i3 * HID + lane];
        a4 += h[i4 * HID + lane];
        a5 += h[i5 * HID + lane];
        a6 += h[i6 * HID + lane];
        a7 += h[i7 * HID + lane];
      }
      for (; k < cnt; ++k) {
        int idx = __shfl(idxv, k);
        a0 += h[idx * HID + lane];
      }
    }
    agg[n * HID + lane] = ((a0 + a1) + (a2 + a3)) + ((a4 + a5) + (a6 + a7));
  }
}

// ------- mlp: out = relu( relu(agg @ W1 + b1) @ W2 + b2 ), one wave per node -------
__global__ __launch_bounds__(256) void mlp_kernel(
    const float* __restrict__ agg, const float* __restrict__ W1,
    const float* __restrict__ b1, const float* __restrict__ W2,
    const float* __restrict__ b2, float* __restrict__ out) {
  __shared__ float sW1[HID * HID];  // 16 KB
  __shared__ float sW2[HID * HID];  // 16 KB
  __shared__ float sb1[HID], sb2[HID];
  for (int i = threadIdx.x; i < HID * HID; i += 256) {
    sW1[i] = W1[i];
    sW2[i] = W2[i];
  }
  if (threadIdx.x < HID) {
    sb1[threadIdx.x] = b1[threadIdx.x];
    sb2[threadIdx.x] = b2[threadIdx.x];
  }
  __syncthreads();
  const int wave = threadIdx.x >> 6, lane = threadIdx.x & 63;
  const int nwaves = gridDim.x * 4;
  for (int n = blockIdx.x * 4 + wave; n < N_NODES; n += nwaves) {
    float in = agg[n * HID + lane];
    float acc = sb1[lane];
#pragma unroll
    for (int k = 0; k < 64; ++k) acc = fmaf(__shfl(in, k), sW1[k * HID + lane], acc);
    float t = fmaxf(acc, 0.0f);
    acc = sb2[lane];
#pragma unroll
    for (int k = 0; k < 64; ++k) acc = fmaf(__shfl(t, k), sW2[k * HID + lane], acc);
    out[n * HID + lane] = fmaxf(acc, 0.0f);
  }
}

// ------- pool: batch sorted -> one block per graph, binary-search range -------
__global__ __launch_bounds__(256) void pool_kernel(const float* __restrict__ h,
                                                   const int* __restrict__ batch,
                                                   float* __restrict__ out) {
  const int g = blockIdx.x;
  int lo = 0, hi = N_NODES;
  while (lo < hi) {
    int mid = (lo + hi) >> 1;
    if (batch[mid] < g) lo = mid + 1; else hi = mid;
  }
  const int s = lo;
  hi = N_NODES;
  while (lo < hi) {
    int mid = (lo + hi) >> 1;
    if (batch[mid] < g + 1) lo = mid + 1; else hi = mid;
  }
  const int e = lo;
  const int wave = threadIdx.x >> 6, lane = threadIdx.x & 63;
  float a0 = 0.f, a1 = 0.f, a2 = 0.f, a3 = 0.f;
  int n = s + wave;
  for (; n + 12 < e; n += 16) {
    a0 += h[n * HID + lane];
    a1 += h[(n + 4) * HID + lane];
    a2 += h[(n + 8) * HID + lane];
    a3 += h[(n + 12) * HID + lane];
  }
  for (; n < e; n += 4) a0 += h[n * HID + lane];
  __shared__ float red[4][HID];
  red[wave][lane] = ((a0 + a1) + (a2 + a3));
  __syncthreads();
  if (wave == 0) {
    float v = red[0][lane] + red[1][lane] + red[2][lane] + red[3][lane];
    float cnt = (float)(e - s);
    out[g * HID + lane] = v / fmaxf(cnt, 1.0f);
  }
}

extern "C" void kernel_launch(void* const* d_in, const int* in_sizes, int n_in,
                              void* d_out, int out_size, void* d_ws, size_t ws_size,
                              hipStream_t stream) {
  const float* x    = (const float*)d_in[0];
  const int*   edge = (const int*)d_in[1];
  const int*   batch= (const int*)d_in[2];
  const float* Wp   = (const float*)d_in[3];
  const float* bp   = (const float*)d_in[4];
  const float* W1_0 = (const float*)d_in[5];
  const float* b1_0 = (const float*)d_in[6];
  const float* W2_0 = (const float*)d_in[7];
  const float* b2_0 = (const float*)d_in[8];
  const float* W1_1 = (const float*)d_in[9];
  const float* b1_1 = (const float*)d_in[10];
  const float* W2_1 = (const float*)d_in[11];
  const float* b2_1 = (const float*)d_in[12];
  const int* src = edge;
  const int* dst = edge + N_EDGES;
  float* out = (float*)d_out;

  const size_t NB = (size_t)N_NODES * HID;
  float* bufA = (float*)d_ws;       // h
  float* bufB = bufA + NB;          // agg
  float* bufC = bufB + NB;          // mlp out
  int* deg       = (int*)(bufC + NB);
  int* off       = deg + N_NODES;
  int* cursor    = off + N_NODES + 1;
  int* blocksum  = cursor + N_NODES;
  int* blockpref = blocksum + SCAN_BLOCKS;
  int* csr       = blockpref + SCAN_BLOCKS;  // 800000 ints

  dim3 b256(256);
  const int EG = (N_EDGES + 255) / 256;

  // CSR build
  hipMemsetAsync(deg, 0, N_NODES * sizeof(int), stream);
  hist_kernel<<<EG, b256, 0, stream>>>(dst, deg);
  scan1_kernel<<<SCAN_BLOCKS, b256, 0, stream>>>(deg, off, blocksum);
  scan2_kernel<<<1, b256, 0, stream>>>(blocksum, blockpref, off);
  scan3_kernel<<<SCAN_BLOCKS, b256, 0, stream>>>(off, blockpref, cursor);
  fill_kernel<<<EG, b256, 0, stream>>>(src, dst, cursor, csr);

  // h0 -> bufA
  proj_kernel<<<2048, b256, 0, stream>>>(x, Wp, bp, bufA);

  // layer 0
  gather_kernel<<<12500, b256, 0, stream>>>(bufA, off, csr, bufB);
  mlp_kernel<<<2048, b256, 0, stream>>>(bufB, W1_0, b1_0, W2_0, b2_0, bufC);

  // layer 1
  gather_kernel<<<12500, b256, 0, stream>>>(bufC, off, csr, bufB);
  mlp_kernel<<<2048, b256, 0, stream>>>(bufB, W1_1, b1_1, W2_1, b2_1, bufA);

  // pool
  pool_kernel<<<N_GRAPHS, b256, 0, stream>>>(bufA, batch, out);
}

// Round 7
// 259.280 us; speedup vs baseline: 6.9515x; 1.5623x over previous
//
#include <hip/hip_runtime.h>

#define N_NODES 50000
#define N_EDGES 800000
#define IN_DIM 128
#define HID 64
#define N_GRAPHS 256
#define SCAN_BLOCKS ((N_NODES + 255) / 256)  // 196

// NOTES:
// (r3-4) __launch_bounds__ min-waves arg => VGPR cap halved, ~1.1 GB scratch spill. Use plain (256).
// (r5)   single-block scan = 125 us latency; hierarchical 3-phase scan now.
// (r6)   wave-per-node GEMV with LDS-resident W = 256 DS ops/node (W re-read 32KB/node + shfl
//        bcast) -> LDS-pipe-bound, 82 us. Now: W columns in per-lane REGISTERS (loaded once,
//        coalesced), input row staged in LDS and read via same-address float4 broadcast.

// ---------------- CSR build: histogram -> 3-phase scan -> fill ----------------
__global__ __launch_bounds__(256) void hist_kernel(const int* __restrict__ dst,
                                                   int* __restrict__ deg) {
  int i = blockIdx.x * 256 + threadIdx.x;
  if (i < N_EDGES) atomicAdd(&deg[dst[i]], 1);
}

__global__ __launch_bounds__(256) void scan1_kernel(const int* __restrict__ deg,
                                                    int* __restrict__ off,
                                                    int* __restrict__ blocksum) {
  __shared__ int s[256];
  const int t = threadIdx.x;
  const int i = blockIdx.x * 256 + t;
  int v = (i < N_NODES) ? deg[i] : 0;
  s[t] = v;
  __syncthreads();
#pragma unroll
  for (int ofs = 1; ofs < 256; ofs <<= 1) {
    int u = (t >= ofs) ? s[t - ofs] : 0;
    __syncthreads();
    s[t] += u;
    __syncthreads();
  }
  if (i < N_NODES) off[i] = s[t] - v;
  if (t == 255) blocksum[blockIdx.x] = s[255];
}

__global__ __launch_bounds__(256) void scan2_kernel(int* __restrict__ blocksum,
                                                    int* __restrict__ blockpref,
                                                    int* __restrict__ off) {
  __shared__ int s[256];
  const int t = threadIdx.x;
  int v = (t < SCAN_BLOCKS) ? blocksum[t] : 0;
  s[t] = v;
  __syncthreads();
#pragma unroll
  for (int ofs = 1; ofs < 256; ofs <<= 1) {
    int u = (t >= ofs) ? s[t - ofs] : 0;
    __syncthreads();
    s[t] += u;
    __syncthreads();
  }
  if (t < SCAN_BLOCKS) blockpref[t] = s[t] - v;
  if (t == 255) off[N_NODES] = s[255];
}

__global__ __launch_bounds__(256) void scan3_kernel(int* __restrict__ off,
                                                    const int* __restrict__ blockpref,
                                                    int* __restrict__ cursor) {
  const int i = blockIdx.x * 256 + threadIdx.x;
  if (i < N_NODES) {
    int o = off[i] + blockpref[blockIdx.x];
    off[i] = o;
    cursor[i] = o;
  }
}

__global__ __launch_bounds__(256) void fill_kernel(const int* __restrict__ src,
                                                   const int* __restrict__ dst,
                                                   int* __restrict__ cursor,
                                                   int* __restrict__ csr) {
  int i = blockIdx.x * 256 + threadIdx.x;
  if (i < N_EDGES) {
    int p = atomicAdd(&cursor[dst[i]], 1);
    csr[p] = src[i];
  }
}

// ---- proj: h = relu(x @ Wp + bp). W column j=lane in registers; input via LDS broadcast ----
__global__ __launch_bounds__(256) void proj_kernel(
    const float* __restrict__ x, const float* __restrict__ Wp,
    const float* __restrict__ bp, float* __restrict__ h) {
  __shared__ float sIn[4][IN_DIM + 4];  // per-wave staging row, padded
  const int wave = threadIdx.x >> 6, lane = threadIdx.x & 63;
  float w[IN_DIM];  // fully unrolled accesses -> registers
#pragma unroll
  for (int k = 0; k < IN_DIM; ++k) w[k] = Wp[k * HID + lane];  // coalesced (lane = j)
  const float bias = bp[lane];
  const int wv = blockIdx.x * 4 + wave;
  const int nw = gridDim.x * 4;
  for (int n = wv; n < N_NODES; n += nw) {
    sIn[wave][lane] = x[n * IN_DIM + lane];
    sIn[wave][64 + lane] = x[n * IN_DIM + 64 + lane];
    float a0 = bias, a1 = 0.f, a2 = 0.f, a3 = 0.f;
#pragma unroll
    for (int k = 0; k < IN_DIM; k += 4) {
      float4 v = *(const float4*)&sIn[wave][k];  // same-addr broadcast read
      a0 = fmaf(v.x, w[k + 0], a0);
      a1 = fmaf(v.y, w[k + 1], a1);
      a2 = fmaf(v.z, w[k + 2], a2);
      a3 = fmaf(v.w, w[k + 3], a3);
    }
    h[n * HID + lane] = fmaxf((a0 + a1) + (a2 + a3), 0.0f);
  }
}

// ------- gather: agg[n] = h[n] + sum_{e} h[csr[e]] ; wave per node, 8-deep ILP -------
__global__ __launch_bounds__(256) void gather_kernel(
    const float* __restrict__ h, const int* __restrict__ off,
    const int* __restrict__ csr, float* __restrict__ agg) {
  const int lane = threadIdx.x & 63;
  const int wv = (blockIdx.x * 256 + threadIdx.x) >> 6;
  const int nw = (gridDim.x * 256) >> 6;
  for (int n = wv; n < N_NODES; n += nw) {
    const int o0 = off[n], o1 = off[n + 1];
    float a0 = h[n * HID + lane];  // self (eps = 0)
    float a1 = 0.f, a2 = 0.f, a3 = 0.f;
    float a4 = 0.f, a5 = 0.f, a6 = 0.f, a7 = 0.f;
    for (int base = o0; base < o1; base += 64) {
      const int cnt = min(64, o1 - base);
      int idxv = (lane < cnt) ? csr[base + lane] : 0;
      int k = 0;
      for (; k + 8 <= cnt; k += 8) {
        int i0 = __shfl(idxv, k + 0), i1 = __shfl(idxv, k + 1);
        int i2 = __shfl(idxv, k + 2), i3 = __shfl(idxv, k + 3);
        int i4 = __shfl(idxv, k + 4), i5 = __shfl(idxv, k + 5);
        int i6 = __shfl(idxv, k + 6), i7 = __shfl(idxv, k + 7);
        a0 += h[i0 * HID + lane];
        a1 += h[i1 * HID + lane];
        a2 += h[i2 * HID + lane];
        a3 += h[i3 * HID + lane];
        a4 += h[i4 * HID + lane];
        a5 += h[i5 * HID + lane];
        a6 += h[i6 * HID + lane];
        a7 += h[i7 * HID + lane];
      }
      for (; k < cnt; ++k) {
        int idx = __shfl(idxv, k);
        a0 += h[idx * HID + lane];
      }
    }
    agg[n * HID + lane] = ((a0 + a1) + (a2 + a3)) + ((a4 + a5) + (a6 + a7));
  }
}

// ---- mlp: out = relu(relu(agg@W1+b1)@W2+b2). W1/W2 columns in registers; LDS broadcast ----
__global__ __launch_bounds__(256) void mlp_kernel(
    const float* __restrict__ agg, const float* __restrict__ W1,
    const float* __restrict__ b1, const float* __restrict__ W2,
    const float* __restrict__ b2, float* __restrict__ out) {
  __shared__ float sIn[4][HID + 4];
  const int wave = threadIdx.x >> 6, lane = threadIdx.x & 63;
  float w1[HID], w2[HID];
#pragma unroll
  for (int k = 0; k < HID; ++k) w1[k] = W1[k * HID + lane];
#pragma unroll
  for (int k = 0; k < HID; ++k) w2[k] = W2[k * HID + lane];
  const float bias1 = b1[lane], bias2 = b2[lane];
  const int wv = blockIdx.x * 4 + wave;
  const int nw = gridDim.x * 4;
  for (int n = wv; n < N_NODES; n += nw) {
    sIn[wave][lane] = agg[n * HID + lane];
    float a0 = bias1, a1 = 0.f, a2 = 0.f, a3 = 0.f;
#pragma unroll
    for (int k = 0; k < HID; k += 4) {
      float4 v = *(const float4*)&sIn[wave][k];
      a0 = fmaf(v.x, w1[k + 0], a0);
      a1 = fmaf(v.y, w1[k + 1], a1);
      a2 = fmaf(v.z, w1[k + 2], a2);
      a3 = fmaf(v.w, w1[k + 3], a3);
    }
    float t = fmaxf((a0 + a1) + (a2 + a3), 0.0f);
    sIn[wave][lane] = t;  // same wave: compiler orders LDS write after reads above
    a0 = bias2; a1 = 0.f; a2 = 0.f; a3 = 0.f;
#pragma unroll
    for (int k = 0; k < HID; k += 4) {
      float4 v = *(const float4*)&sIn[wave][k];
      a0 = fmaf(v.x, w2[k + 0], a0);
      a1 = fmaf(v.y, w2[k + 1], a1);
      a2 = fmaf(v.z, w2[k + 2], a2);
      a3 = fmaf(v.w, w2[k + 3], a3);
    }
    out[n * HID + lane] = fmaxf((a0 + a1) + (a2 + a3), 0.0f);
  }
}

// ------- pool: batch sorted -> one block per graph, binary-search range -------
__global__ __launch_bounds__(256) void pool_kernel(const float* __restrict__ h,
                                                   const int* __restrict__ batch,
                                                   float* __restrict__ out) {
  const int g = blockIdx.x;
  int lo = 0, hi = N_NODES;
  while (lo < hi) {
    int mid = (lo + hi) >> 1;
    if (batch[mid] < g) lo = mid + 1; else hi = mid;
  }
  const int s = lo;
  hi = N_NODES;
  while (lo < hi) {
    int mid = (lo + hi) >> 1;
    if (batch[mid] < g + 1) lo = mid + 1; else hi = mid;
  }
  const int e = lo;
  const int wave = threadIdx.x >> 6, lane = threadIdx.x & 63;
  float a0 = 0.f, a1 = 0.f, a2 = 0.f, a3 = 0.f;
  int n = s + wave;
  for (; n + 12 < e; n += 16) {
    a0 += h[n * HID + lane];
    a1 += h[(n + 4) * HID + lane];
    a2 += h[(n + 8) * HID + lane];
    a3 += h[(n + 12) * HID + lane];
  }
  for (; n < e; n += 4) a0 += h[n * HID + lane];
  __shared__ float red[4][HID];
  red[wave][lane] = ((a0 + a1) + (a2 + a3));
  __syncthreads();
  if (wave == 0) {
    float v = red[0][lane] + red[1][lane] + red[2][lane] + red[3][lane];
    float cnt = (float)(e - s);
    out[g * HID + lane] = v / fmaxf(cnt, 1.0f);
  }
}

extern "C" void kernel_launch(void* const* d_in, const int* in_sizes, int n_in,
                              void* d_out, int out_size, void* d_ws, size_t ws_size,
                              hipStream_t stream) {
  const float* x    = (const float*)d_in[0];
  const int*   edge = (const int*)d_in[1];
  const int*   batch= (const int*)d_in[2];
  const float* Wp   = (const float*)d_in[3];
  const float* bp   = (const float*)d_in[4];
  const float* W1_0 = (const float*)d_in[5];
  const float* b1_0 = (const float*)d_in[6];
  const float* W2_0 = (const float*)d_in[7];
  const float* b2_0 = (const float*)d_in[8];
  const float* W1_1 = (const float*)d_in[9];
  const float* b1_1 = (const float*)d_in[10];
  const float* W2_1 = (const float*)d_in[11];
  const float* b2_1 = (const float*)d_in[12];
  const int* src = edge;
  const int* dst = edge + N_EDGES;
  float* out = (float*)d_out;

  const size_t NB = (size_t)N_NODES * HID;
  float* bufA = (float*)d_ws;       // h
  float* bufB = bufA + NB;          // agg
  float* bufC = bufB + NB;          // mlp out
  int* deg       = (int*)(bufC + NB);
  int* off       = deg + N_NODES;
  int* cursor    = off + N_NODES + 1;
  int* blocksum  = cursor + N_NODES;
  int* blockpref = blocksum + SCAN_BLOCKS;
  int* csr       = blockpref + SCAN_BLOCKS;  // 800000 ints

  dim3 b256(256);
  const int EG = (N_EDGES + 255) / 256;

  // CSR build
  hipMemsetAsync(deg, 0, N_NODES * sizeof(int), stream);
  hist_kernel<<<EG, b256, 0, stream>>>(dst, deg);
  scan1_kernel<<<SCAN_BLOCKS, b256, 0, stream>>>(deg, off, blocksum);
  scan2_kernel<<<1, b256, 0, stream>>>(blocksum, blockpref, off);
  scan3_kernel<<<SCAN_BLOCKS, b256, 0, stream>>>(off, blockpref, cursor);
  fill_kernel<<<EG, b256, 0, stream>>>(src, dst, cursor, csr);

  // h0 -> bufA
  proj_kernel<<<1024, b256, 0, stream>>>(x, Wp, bp, bufA);

  // layer 0
  gather_kernel<<<12500, b256, 0, stream>>>(bufA, off, csr, bufB);
  mlp_kernel<<<1024, b256, 0, stream>>>(bufB, W1_0, b1_0, W2_0, b2_0, bufC);

  // layer 1
  gather_kernel<<<12500, b256, 0, stream>>>(bufC, off, csr, bufB);
  mlp_kernel<<<1024, b256, 0, stream>>>(bufB, W1_1, b1_1, W2_1, b2_1, bufA);

  // pool
  pool_kernel<<<N_GRAPHS, b256, 0, stream>>>(bufA, batch, out);
}

// Round 8
// 200.414 us; speedup vs baseline: 8.9933x; 1.2937x over previous
//
#include <hip/hip_runtime.h>

#define N_NODES 50000
#define N_EDGES 800000
#define IN_DIM 128
#define HID 64
#define N_GRAPHS 256

#define E_PER_BLK 4000
#define F_BLOCKS (N_EDGES / E_PER_BLK)      // 200
#define NBKT ((N_NODES + 255) / 256)        // 196 coarse buckets of 256 nodes
#define CNT_N (NBKT * F_BLOCKS)             // 39200
#define SCB ((CNT_N + 255) / 256)           // 154

// NOTES:
// (r3-4) __launch_bounds__ min-waves arg => VGPR cap halved, ~1.1 GB scratch spill. Plain (256).
// (r5)   single-block scan = 125 us one-CU latency; hierarchical scans only.
// (r6)   GEMV with LDS-resident W was LDS-pipe-bound; W columns now live in registers.
// (r7)   atomic-cursor CSR fill = 53 us (800K returning device-scope atomics, 16x write
//        amplification). Replaced with two-level LDS counting sort: zero global atomics,
//        csr written in per-bucket contiguous windows.

// ---- F1: per-(block, coarse-bucket) histogram of dst ----
__global__ __launch_bounds__(256) void part_hist_kernel(const int* __restrict__ dst,
                                                        int* __restrict__ cnt) {
  __shared__ int h[NBKT];
  const int t = threadIdx.x;
  for (int k = t; k < NBKT; k += 256) h[k] = 0;
  __syncthreads();
  const int base = blockIdx.x * E_PER_BLK;
  for (int i = t; i < E_PER_BLK; i += 256) atomicAdd(&h[dst[base + i] >> 8], 1);
  __syncthreads();
  for (int k = t; k < NBKT; k += 256) cnt[k * F_BLOCKS + blockIdx.x] = h[k];
}

// ---- F2: flat hierarchical exclusive scan over CNT_N entries ----
__global__ __launch_bounds__(256) void scan1g_kernel(const int* __restrict__ in,
                                                     int* __restrict__ ex,
                                                     int* __restrict__ bsum, int n) {
  __shared__ int s[256];
  const int t = threadIdx.x;
  const int i = blockIdx.x * 256 + t;
  int v = (i < n) ? in[i] : 0;
  s[t] = v;
  __syncthreads();
#pragma unroll
  for (int ofs = 1; ofs < 256; ofs <<= 1) {
    int u = (t >= ofs) ? s[t - ofs] : 0;
    __syncthreads();
    s[t] += u;
    __syncthreads();
  }
  if (i < n) ex[i] = s[t] - v;
  if (t == 255) bsum[blockIdx.x] = s[255];
}

__global__ __launch_bounds__(256) void scan2g_kernel(const int* __restrict__ bsum,
                                                     int* __restrict__ bpref, int nb) {
  __shared__ int s[256];
  const int t = threadIdx.x;
  int v = (t < nb) ? bsum[t] : 0;
  s[t] = v;
  __syncthreads();
#pragma unroll
  for (int ofs = 1; ofs < 256; ofs <<= 1) {
    int u = (t >= ofs) ? s[t - ofs] : 0;
    __syncthreads();
    s[t] += u;
    __syncthreads();
  }
  if (t < nb) bpref[t] = s[t] - v;
}

__global__ __launch_bounds__(256) void scan3g_kernel(int* __restrict__ ex,
                                                     const int* __restrict__ bpref, int n) {
  const int i = blockIdx.x * 256 + threadIdx.x;
  if (i < n) ex[i] += bpref[blockIdx.x];
}

// ---- F3: partition edges into coarse-bucket order (LDS cursors, run-coalesced writes) ----
__global__ __launch_bounds__(256) void part_scatter_kernel(const int* __restrict__ src,
                                                           const int* __restrict__ dst,
                                                           const int* __restrict__ cex,
                                                           int* __restrict__ psrc,
                                                           int* __restrict__ pdst) {
  __shared__ int cur[NBKT];
  const int t = threadIdx.x;
  for (int k = t; k < NBKT; k += 256) cur[k] = cex[k * F_BLOCKS + blockIdx.x];
  __syncthreads();
  const int base = blockIdx.x * E_PER_BLK;
  for (int i = t; i < E_PER_BLK; i += 256) {
    int d = dst[base + i], s = src[base + i];
    int p = atomicAdd(&cur[d >> 8], 1);
    pdst[p] = d;
    psrc[p] = s;
  }
}

// ---- F4: per-bucket local counting sort -> csr + off (contiguous 16KB window/block) ----
__global__ __launch_bounds__(256) void bucket_sort_kernel(const int* __restrict__ psrc,
                                                          const int* __restrict__ pdst,
                                                          const int* __restrict__ cex,
                                                          int* __restrict__ csr,
                                                          int* __restrict__ off) {
  const int k = blockIdx.x;
  const int t = threadIdx.x;
  const int b0 = cex[k * F_BLOCKS];
  const int b1 = (k == NBKT - 1) ? N_EDGES : cex[(k + 1) * F_BLOCKS];
  __shared__ int cnt[256];
  __shared__ int s[256];
  __shared__ int cur[256];
  cnt[t] = 0;
  __syncthreads();
  for (int i = b0 + t; i < b1; i += 256) atomicAdd(&cnt[pdst[i] & 255], 1);
  __syncthreads();
  int v = cnt[t];
  s[t] = v;
  __syncthreads();
#pragma unroll
  for (int ofs = 1; ofs < 256; ofs <<= 1) {
    int u = (t >= ofs) ? s[t - ofs] : 0;
    __syncthreads();
    s[t] += u;
    __syncthreads();
  }
  const int node = (k << 8) + t;
  const int start = b0 + s[t] - v;  // exclusive
  cur[t] = start;
  if (node < N_NODES) off[node] = start;
  if (k == NBKT - 1 && t == 0) off[N_NODES] = N_EDGES;
  __syncthreads();
  for (int i = b0 + t; i < b1; i += 256) {
    int d = pdst[i];
    int p = atomicAdd(&cur[d & 255], 1);
    csr[p] = psrc[i];
  }
}

// ---- proj: h = relu(x @ Wp + bp). W column j=lane in registers; input via LDS broadcast ----
__global__ __launch_bounds__(256) void proj_kernel(
    const float* __restrict__ x, const float* __restrict__ Wp,
    const float* __restrict__ bp, float* __restrict__ h) {
  __shared__ float sIn[4][IN_DIM + 4];
  const int wave = threadIdx.x >> 6, lane = threadIdx.x & 63;
  float w[IN_DIM];
#pragma unroll
  for (int k = 0; k < IN_DIM; ++k) w[k] = Wp[k * HID + lane];  // coalesced (lane = j)
  const float bias = bp[lane];
  const int wv = blockIdx.x * 4 + wave;
  const int nw = gridDim.x * 4;
  for (int n = wv; n < N_NODES; n += nw) {
    sIn[wave][lane] = x[n * IN_DIM + lane];
    sIn[wave][64 + lane] = x[n * IN_DIM + 64 + lane];
    float a0 = bias, a1 = 0.f, a2 = 0.f, a3 = 0.f;
#pragma unroll
    for (int k = 0; k < IN_DIM; k += 4) {
      float4 v = *(const float4*)&sIn[wave][k];  // same-addr broadcast read
      a0 = fmaf(v.x, w[k + 0], a0);
      a1 = fmaf(v.y, w[k + 1], a1);
      a2 = fmaf(v.z, w[k + 2], a2);
      a3 = fmaf(v.w, w[k + 3], a3);
    }
    h[n * HID + lane] = fmaxf((a0 + a1) + (a2 + a3), 0.0f);
  }
}

// ------- gather: agg[n] = h[n] + sum_{e} h[csr[e]] ; wave per node, 8-deep ILP -------
__global__ __launch_bounds__(256) void gather_kernel(
    const float* __restrict__ h, const int* __restrict__ off,
    const int* __restrict__ csr, float* __restrict__ agg) {
  const int lane = threadIdx.x & 63;
  const int wv = (blockIdx.x * 256 + threadIdx.x) >> 6;
  const int nw = (gridDim.x * 256) >> 6;
  for (int n = wv; n < N_NODES; n += nw) {
    const int o0 = off[n], o1 = off[n + 1];
    float a0 = h[n * HID + lane];  // self (eps = 0)
    float a1 = 0.f, a2 = 0.f, a3 = 0.f;
    float a4 = 0.f, a5 = 0.f, a6 = 0.f, a7 = 0.f;
    for (int base = o0; base < o1; base += 64) {
      const int cnt = min(64, o1 - base);
      int idxv = (lane < cnt) ? csr[base + lane] : 0;
      int k = 0;
      for (; k + 8 <= cnt; k += 8) {
        int i0 = __shfl(idxv, k + 0), i1 = __shfl(idxv, k + 1);
        int i2 = __shfl(idxv, k + 2), i3 = __shfl(idxv, k + 3);
        int i4 = __shfl(idxv, k + 4), i5 = __shfl(idxv, k + 5);
        int i6 = __shfl(idxv, k + 6), i7 = __shfl(idxv, k + 7);
        a0 += h[i0 * HID + lane];
        a1 += h[i1 * HID + lane];
        a2 += h[i2 * HID + lane];
        a3 += h[i3 * HID + lane];
        a4 += h[i4 * HID + lane];
        a5 += h[i5 * HID + lane];
        a6 += h[i6 * HID + lane];
        a7 += h[i7 * HID + lane];
      }
      for (; k < cnt; ++k) {
        int idx = __shfl(idxv, k);
        a0 += h[idx * HID + lane];
      }
    }
    agg[n * HID + lane] = ((a0 + a1) + (a2 + a3)) + ((a4 + a5) + (a6 + a7));
  }
}

// ---- mlp (in-place safe): out = relu(relu(in@W1+b1)@W2+b2); W cols in registers ----
__global__ __launch_bounds__(256) void mlp_kernel(
    const float* __restrict__ agg, const float* __restrict__ W1,
    const float* __restrict__ b1, const float* __restrict__ W2,
    const float* __restrict__ b2, float* __restrict__ out) {
  __shared__ float sIn[4][HID + 4];
  const int wave = threadIdx.x >> 6, lane = threadIdx.x & 63;
  float w1[HID], w2[HID];
#pragma unroll
  for (int k = 0; k < HID; ++k) w1[k] = W1[k * HID + lane];
#pragma unroll
  for (int k = 0; k < HID; ++k) w2[k] = W2[k * HID + lane];
  const float bias1 = b1[lane], bias2 = b2[lane];
  const int wv = blockIdx.x * 4 + wave;
  const int nw = gridDim.x * 4;
  for (int n = wv; n < N_NODES; n += nw) {
    sIn[wave][lane] = agg[n * HID + lane];
    float a0 = bias1, a1 = 0.f, a2 = 0.f, a3 = 0.f;
#pragma unroll
    for (int k = 0; k < HID; k += 4) {
      float4 v = *(const float4*)&sIn[wave][k];
      a0 = fmaf(v.x, w1[k + 0], a0);
      a1 = fmaf(v.y, w1[k + 1], a1);
      a2 = fmaf(v.z, w1[k + 2], a2);
      a3 = fmaf(v.w, w1[k + 3], a3);
    }
    float t = fmaxf((a0 + a1) + (a2 + a3), 0.0f);
    sIn[wave][lane] = t;
    a0 = bias2; a1 = 0.f; a2 = 0.f; a3 = 0.f;
#pragma unroll
    for (int k = 0; k < HID; k += 4) {
      float4 v = *(const float4*)&sIn[wave][k];
      a0 = fmaf(v.x, w2[k + 0], a0);
      a1 = fmaf(v.y, w2[k + 1], a1);
      a2 = fmaf(v.z, w2[k + 2], a2);
      a3 = fmaf(v.w, w2[k + 3], a3);
    }
    out[n * HID + lane] = fmaxf((a0 + a1) + (a2 + a3), 0.0f);
  }
}

// ------- pool: batch sorted -> one block per graph, binary-search range -------
__global__ __launch_bounds__(256) void pool_kernel(const float* __restrict__ h,
                                                   const int* __restrict__ batch,
                                                   float* __restrict__ out) {
  const int g = blockIdx.x;
  int lo = 0, hi = N_NODES;
  while (lo < hi) {
    int mid = (lo + hi) >> 1;
    if (batch[mid] < g) lo = mid + 1; else hi = mid;
  }
  const int s = lo;
  hi = N_NODES;
  while (lo < hi) {
    int mid = (lo + hi) >> 1;
    if (batch[mid] < g + 1) lo = mid + 1; else hi = mid;
  }
  const int e = lo;
  const int wave = threadIdx.x >> 6, lane = threadIdx.x & 63;
  float a0 = 0.f, a1 = 0.f, a2 = 0.f, a3 = 0.f;
  int n = s + wave;
  for (; n + 12 < e; n += 16) {
    a0 += h[n * HID + lane];
    a1 += h[(n + 4) * HID + lane];
    a2 += h[(n + 8) * HID + lane];
    a3 += h[(n + 12) * HID + lane];
  }
  for (; n < e; n += 4) a0 += h[n * HID + lane];
  __shared__ float red[4][HID];
  red[wave][lane] = ((a0 + a1) + (a2 + a3));
  __syncthreads();
  if (wave == 0) {
    float v = red[0][lane] + red[1][lane] + red[2][lane] + red[3][lane];
    float cnt = (float)(e - s);
    out[g * HID + lane] = v / fmaxf(cnt, 1.0f);
  }
}

extern "C" void kernel_launch(void* const* d_in, const int* in_sizes, int n_in,
                              void* d_out, int out_size, void* d_ws, size_t ws_size,
                              hipStream_t stream) {
  const float* x    = (const float*)d_in[0];
  const int*   edge = (const int*)d_in[1];
  const int*   batch= (const int*)d_in[2];
  const float* Wp   = (const float*)d_in[3];
  const float* bp   = (const float*)d_in[4];
  const float* W1_0 = (const float*)d_in[5];
  const float* b1_0 = (const float*)d_in[6];
  const float* W2_0 = (const float*)d_in[7];
  const float* b2_0 = (const float*)d_in[8];
  const float* W1_1 = (const float*)d_in[9];
  const float* b1_1 = (const float*)d_in[10];
  const float* W2_1 = (const float*)d_in[11];
  const float* b2_1 = (const float*)d_in[12];
  const int* src = edge;
  const int* dst = edge + N_EDGES;
  float* out = (float*)d_out;

  const size_t NB = (size_t)N_NODES * HID;
  float* bufA  = (float*)d_ws;      // h / mlp out (mlp runs in-place)
  float* bufB  = bufA + NB;
  int* off     = (int*)(bufB + NB); // N_NODES+1
  int* cnt     = off + N_NODES + 1; // CNT_N
  int* cex     = cnt + CNT_N;       // CNT_N
  int* sbsum   = cex + CNT_N;       // SCB
  int* sbpref  = sbsum + SCB;       // SCB
  int* pdst    = sbpref + SCB;      // N_EDGES
  int* psrc    = pdst + N_EDGES;    // N_EDGES
  int* csr     = psrc + N_EDGES;    // N_EDGES

  dim3 b256(256);

  // CSR build: counting sort, zero global atomics
  part_hist_kernel<<<F_BLOCKS, b256, 0, stream>>>(dst, cnt);
  scan1g_kernel<<<SCB, b256, 0, stream>>>(cnt, cex, sbsum, CNT_N);
  scan2g_kernel<<<1, b256, 0, stream>>>(sbsum, sbpref, SCB);
  scan3g_kernel<<<SCB, b256, 0, stream>>>(cex, sbpref, CNT_N);
  part_scatter_kernel<<<F_BLOCKS, b256, 0, stream>>>(src, dst, cex, psrc, pdst);
  bucket_sort_kernel<<<NBKT, b256, 0, stream>>>(psrc, pdst, cex, csr, off);

  // h0 -> bufA
  proj_kernel<<<1024, b256, 0, stream>>>(x, Wp, bp, bufA);

  // layer 0: gather A->B, mlp B->B (in-place)
  gather_kernel<<<12500, b256, 0, stream>>>(bufA, off, csr, bufB);
  mlp_kernel<<<1024, b256, 0, stream>>>(bufB, W1_0, b1_0, W2_0, b2_0, bufB);

  // layer 1: gather B->A, mlp A->A (in-place)
  gather_kernel<<<12500, b256, 0, stream>>>(bufB, off, csr, bufA);
  mlp_kernel<<<1024, b256, 0, stream>>>(bufA, W1_1, b1_1, W2_1, b2_1, bufA);

  // pool
  pool_kernel<<<N_GRAPHS, b256, 0, stream>>>(bufA, batch, out);
}